// Round 2
// baseline (19689.842 us; speedup 1.0000x reference)
//
#include <hip/hip_runtime.h>
#include <math.h>

// Neuralsymbol scan: B=128 rows x T=128 steps, V=512, H=1024, 4-slot soft stacks.
// R1: identical resubmit of the R0 fp32 correctness baseline (R0 bench hit
// GPUAcquisitionTimeout — no data). 3 kernels/step (KA first-layer GEMMs,
// KB second-layer GEMMs, KC per-row finish + next-step prep). All nl()
// normalizations folded as post-scales; weight row norms precomputed once (Knorm).

#define BB 128
#define TT 128
#define VV 512
#define HH 1024

struct Params {
  const float *x, *Wisin1, *Wisin2, *copW1, *copb1, *copW2, *copb2,
              *wopW1, *wopb1, *wopW2, *wopb2, *ctrlW1, *ctrlW2, *workW1, *workW2,
              *selW1, *selW2, *osym, *initv, *csharp, *wsharp;
  float *cS, *cp, *wS, *wp, *wvec, *xy, *wxy, *sxy, *ixy, *iwxy, *isxy,
        *zP, *kbP, *invW, *out;
};

// ---------------- reductions (256-thread blocks, 4 waves) ----------------
__device__ inline float block_sum(float v, volatile float* sc) {
#pragma unroll
  for (int off = 32; off; off >>= 1) v += __shfl_down(v, off, 64);
  __syncthreads();                      // guard previous use of sc
  if ((threadIdx.x & 63) == 0) sc[threadIdx.x >> 6] = v;
  __syncthreads();
  return sc[0] + sc[1] + sc[2] + sc[3];
}

// online (max, sum e^{z-max}, sum e^{z-max}*w) merge across 256 threads
__device__ inline void block_softdot(float& m, float& s, float& w, volatile float* sc) {
#pragma unroll
  for (int off = 32; off; off >>= 1) {
    float m2 = __shfl_down(m, off, 64);
    float s2 = __shfl_down(s, off, 64);
    float w2 = __shfl_down(w, off, 64);
    float M = fmaxf(m, m2);
    float e1 = __expf(m - M), e2 = __expf(m2 - M);
    s = s * e1 + s2 * e2;
    w = w * e1 + w2 * e2;
    m = M;
  }
  __syncthreads();
  if ((threadIdx.x & 63) == 0) {
    int wid = threadIdx.x >> 6;
    sc[wid * 3 + 0] = m; sc[wid * 3 + 1] = s; sc[wid * 3 + 2] = w;
  }
  __syncthreads();
  float M = sc[0], S = sc[1], W = sc[2];
#pragma unroll
  for (int i = 1; i < 4; ++i) {
    float m2 = sc[i * 3], s2 = sc[i * 3 + 1], w2 = sc[i * 3 + 2];
    float nm = fmaxf(M, m2);
    float e1 = __expf(M - nm), e2 = __expf(m2 - nm);
    S = S * e1 + s2 * e2; W = W * e1 + w2 * e2; M = nm;
  }
  m = M; s = S; w = W;
}

// ---------------- Knorm: inverse row norms of normalized-weight matrices ----------------
__global__ __launch_bounds__(256) void Knorm(Params P) {
  int row = blockIdx.x * 4 + (threadIdx.x >> 6);
  if (row >= 4612) return;
  int lane = threadIdx.x & 63;
  const float* src; int K; int dst;
  if (row < 4)        { src = P.Wisin1 + row * 512;            K = 512;  dst = row; }
  else if (row < 516) { int v = row - 4;    src = P.Wisin2 + v * 4;    K = 4;    dst = 4 + v; }
  else if (row < 1540){ int h = row - 516;  src = P.ctrlW1 + h * 512;  K = 512;  dst = 516 + h; }
  else if (row < 2052){ int v = row - 1540; src = P.ctrlW2 + v * 1024; K = 1024; dst = 1540 + v; }
  else if (row < 3076){ int h = row - 2052; src = P.workW1 + h * 512;  K = 512;  dst = 2052 + h; }
  else if (row < 3588){ int v = row - 3076; src = P.workW2 + v * 1024; K = 1024; dst = 3076 + v; }
  else                { int h = row - 3588; src = P.selW1 + h * 512;   K = 512;  dst = 3588 + h; }
  float s = 0.f;
  for (int k = lane; k < K; k += 64) { float x = src[k]; s += x * x; }
#pragma unroll
  for (int off = 32; off; off >>= 1) s += __shfl_down(s, off, 64);
  if (lane == 0) P.invW[dst] = 1.f / fmaxf(sqrtf(s), 1e-12f);
}

// ---------------- prep: pop stacks, typ, xy/wxy/sxy (+norm scalars) for step tn ----------------
__device__ void prep_step(const Params& P, int b, int tn,
                          const float pcn[4], const float pwn[4],
                          const float newC[4][2], const float newW[4][2],
                          volatile float* sc) {
  int tid = threadIdx.x;
  // write rolled (post-pop) pointers
  if (tid == 0) {
#pragma unroll
    for (int n = 0; n < 4; ++n) {
      P.cp[b * 4 + n] = pcn[(n + 1) & 3];
      P.wp[b * 4 + n] = pwn[(n + 1) & 3];
    }
  }
  float ctl[2], wrk[2], inp[2];
#pragma unroll
  for (int i = 0; i < 2; ++i) {
    int v = tid + i * 256;
    float c = 0.f, w = 0.f;
#pragma unroll
    for (int n = 0; n < 4; ++n) { c += pcn[n] * newC[n][i]; w += pwn[n] * newW[n][i]; }
    ctl[i] = c; wrk[i] = w;
    P.wvec[b * 512 + v] = w;
    inp[i] = P.x[(b * TT + tn) * 512 + v];
  }
  // reduce: ||inp||^2 and 4 dots with W_isin1
  float r0 = inp[0] * inp[0] + inp[1] * inp[1];
  float d[4];
#pragma unroll
  for (int j = 0; j < 4; ++j)
    d[j] = inp[0] * P.Wisin1[j * 512 + tid] + inp[1] * P.Wisin1[j * 512 + tid + 256];
  r0 = block_sum(r0, sc);
#pragma unroll
  for (int j = 0; j < 4; ++j) d[j] = block_sum(d[j], sc);
  float inv_in = 1.f / fmaxf(sqrtf(r0), 1e-12f);
  // relu -> softmax4 -> normalize (redundant on all threads; deterministic)
  float a[4];
#pragma unroll
  for (int j = 0; j < 4; ++j) a[j] = fmaxf(d[j] * inv_in * P.invW[j], 0.f);
  float mx = fmaxf(fmaxf(a[0], a[1]), fmaxf(a[2], a[3]));
  float e[4], es = 0.f;
#pragma unroll
  for (int j = 0; j < 4; ++j) { e[j] = __expf(a[j] - mx); es += e[j]; }
  float q[4], qs = 0.f;
#pragma unroll
  for (int j = 0; j < 4; ++j) { q[j] = e[j] / es; qs += q[j] * q[j]; }
  float qi = 1.f / fmaxf(sqrtf(qs), 1e-12f);
  float qn[4];
#pragma unroll
  for (int j = 0; j < 4; ++j) qn[j] = q[j] * qi;

  float xys = 0.f, wxs = 0.f, sxs = 0.f;
#pragma unroll
  for (int i = 0; i < 2; ++i) {
    int v = tid + i * 256;
    float dq = 0.f;
#pragma unroll
    for (int j = 0; j < 4; ++j) dq += qn[j] * P.Wisin2[v * 4 + j];
    float typ = tanhf(dq * P.invW[4 + v]);
    float xyv = ctl[i] * typ;
    float wxv = wrk[i] * inp[i] * typ;
    float sxv = ctl[i] * wrk[i] * typ;
    P.xy[b * 512 + v] = xyv;
    P.wxy[b * 512 + v] = wxv;
    P.sxy[b * 512 + v] = sxv;
    xys += xyv * xyv; wxs += wxv * wxv; sxs += sxv * sxv;
  }
  xys = block_sum(xys, sc);
  wxs = block_sum(wxs, sc);
  sxs = block_sum(sxs, sc);
  if (tid == 0) {
    P.ixy[b]  = 1.f / fmaxf(sqrtf(xys), 1e-12f);
    P.iwxy[b] = 1.f / fmaxf(sqrtf(wxs), 1e-12f);
    P.isxy[b] = 1.f / fmaxf(sqrtf(sxs), 1e-12f);
  }
}

// ---------------- K0: init stacks (hard push of init vec) + prep(t=0) ----------------
__global__ __launch_bounds__(256) void K0(Params P) {
  __shared__ float sc[16];
  int b = blockIdx.x, tid = threadIdx.x;
  float newC[4][2], newW[4][2];
#pragma unroll
  for (int i = 0; i < 2; ++i) {
    int v = tid + i * 256;
    float iv = P.initv[v];
#pragma unroll
    for (int n = 0; n < 4; ++n) {
      float val = (n == 1) ? iv : 1e-6f;
      P.cS[(b * 4 + n) * 512 + v] = val;
      P.wS[(b * 4 + n) * 512 + v] = val;
      newC[n][i] = val; newW[n][i] = val;
    }
  }
  float p0[4] = {0.f, 1.f, 0.f, 0.f};   // pointer after initial hard push
  __syncthreads();
  prep_step(P, b, 0, p0, p0, newC, newW, sc);
}

// ---------------- KA: 9 first-layer GEMMs, raw dots, K split in 2 ----------------
// grid 144: w = m*16 + ks*8 + ctile ; tile = 128 cols x 128 rows x K256
__global__ __launch_bounds__(256) void KA(Params P) {
  int w = blockIdx.x;
  int m = w >> 4, ks = (w >> 3) & 1, ct = w & 7;
  const float* X = (m <= 6) ? P.xy : (m == 7 ? P.wxy : P.sxy);
  const float* W;
  if (m < 3)      W = P.copW1 + m * (1024 * 512);
  else if (m < 6) W = P.wopW1 + (m - 3) * (1024 * 512);
  else if (m == 6) W = P.ctrlW1;
  else if (m == 7) W = P.workW1;
  else             W = P.selW1;
  int h0 = ct * 128, k0 = ks * 256;
  __shared__ float xt[32][132];
  __shared__ float wt[32][132];
  float acc[8][8];
#pragma unroll
  for (int j = 0; j < 8; ++j)
#pragma unroll
    for (int i = 0; i < 8; ++i) acc[j][i] = 0.f;
  int cg = threadIdx.x & 15, rg = threadIdx.x >> 4;
  for (int kc = 0; kc < 256; kc += 32) {
#pragma unroll
    for (int i = 0; i < 16; ++i) {
      int flat = i * 256 + threadIdx.x;
      int r = flat >> 5, k = flat & 31;
      xt[k][r] = X[r * 512 + k0 + kc + k];
      wt[k][r] = W[(h0 + r) * 512 + k0 + kc + k];
    }
    __syncthreads();
    for (int k = 0; k < 32; ++k) {
      float a[8], bb[8];
      *(float4*)&a[0] = *(const float4*)&xt[k][rg * 8];
      *(float4*)&a[4] = *(const float4*)&xt[k][rg * 8 + 4];
      *(float4*)&bb[0] = *(const float4*)&wt[k][cg * 8];
      *(float4*)&bb[4] = *(const float4*)&wt[k][cg * 8 + 4];
#pragma unroll
      for (int j = 0; j < 8; ++j)
#pragma unroll
        for (int i = 0; i < 8; ++i) acc[j][i] = fmaf(a[j], bb[i], acc[j][i]);
    }
    __syncthreads();
  }
#pragma unroll
  for (int j = 0; j < 8; ++j) {
    int r = rg * 8 + j;
    float* dst = P.zP + ((m * 2 + ks) * 128 + r) * 1024 + h0 + cg * 8;
    float4 v0 = make_float4(acc[j][0], acc[j][1], acc[j][2], acc[j][3]);
    float4 v1 = make_float4(acc[j][4], acc[j][5], acc[j][6], acc[j][7]);
    *(float4*)&dst[0] = v0;
    *(float4*)&dst[4] = v1;
  }
}

// ---------------- KB: second-layer GEMMs (relu + fold scales on load), K split in 8 ----------------
// grid 136: w = tile*8 + ks ; tile<8 ctrl cols, 8..15 work cols, 16 sel (5 cols)
__global__ __launch_bounds__(128) void KB(Params P) {
  int w = blockIdx.x;
  int ks = w & 7, tile = w >> 3;
  int zm = (tile < 8) ? 6 : (tile < 16 ? 7 : 8);
  int colbase = (tile < 16) ? tile * 64 : 1024;
  int k0 = ks * 128;
  __shared__ float at[32][132];
  __shared__ float wt2[32][68];
  float acc[8][8];
#pragma unroll
  for (int j = 0; j < 8; ++j)
#pragma unroll
    for (int i = 0; i < 8; ++i) acc[j][i] = 0.f;
  int cg = threadIdx.x & 7, rg = threadIdx.x >> 3;
  const float* zb0 = P.zP + (zm * 2) * (128 * 1024);
  const float* zb1 = zb0 + 128 * 1024;
  const float* ix = (zm == 6) ? P.ixy : (zm == 7 ? P.iwxy : P.isxy);
  int ioff = (zm == 6) ? 516 : (zm == 7 ? 2052 : 3588);
  for (int kc = 0; kc < 128; kc += 32) {
#pragma unroll
    for (int i = 0; i < 32; ++i) {
      int flat = i * 128 + threadIdx.x;
      int r = flat >> 5, k = flat & 31;
      int h = k0 + kc + k;
      float z = zb0[r * 1024 + h] + zb1[r * 1024 + h];
      at[k][r] = fmaxf(z * (ix[r] * P.invW[ioff + h]), 0.f);
    }
#pragma unroll
    for (int i = 0; i < 16; ++i) {
      int flat = i * 128 + threadIdx.x;
      int c = flat >> 5, k = flat & 31;
      int h = k0 + kc + k;
      float val;
      if (tile < 8)       val = P.ctrlW2[(tile * 64 + c) * 1024 + h];
      else if (tile < 16) val = P.workW2[((tile - 8) * 64 + c) * 1024 + h];
      else                val = (c < 5) ? P.selW2[c * 1024 + h] : 0.f;
      wt2[k][c] = val;
    }
    __syncthreads();
    for (int k = 0; k < 32; ++k) {
      float a[8], bb[8];
      *(float4*)&a[0] = *(const float4*)&at[k][rg * 8];
      *(float4*)&a[4] = *(const float4*)&at[k][rg * 8 + 4];
      *(float4*)&bb[0] = *(const float4*)&wt2[k][cg * 8];
      *(float4*)&bb[4] = *(const float4*)&wt2[k][cg * 8 + 4];
#pragma unroll
      for (int j = 0; j < 8; ++j)
#pragma unroll
        for (int i = 0; i < 8; ++i) acc[j][i] = fmaf(a[j], bb[i], acc[j][i]);
    }
    __syncthreads();
  }
#pragma unroll
  for (int j = 0; j < 8; ++j) {
    int r = rg * 8 + j;
    int col = colbase + cg * 8;
    if (col + 8 <= 1032) {
      float* dst = P.kbP + (ks * 128 + r) * 1032 + col;
      float4 v0 = make_float4(acc[j][0], acc[j][1], acc[j][2], acc[j][3]);
      float4 v1 = make_float4(acc[j][4], acc[j][5], acc[j][6], acc[j][7]);
      *(float4*)&dst[0] = v0;
      *(float4*)&dst[4] = v1;
    }
  }
}

// ---------------- KC: gates, norms, sel, out, stack soft-ops, + prep(t+1) ----------------
__global__ __launch_bounds__(256) void KC(Params P, int t) {
  __shared__ float sc[16];
  __shared__ float shg[6];
  __shared__ float shsel[5];
  int b = blockIdx.x, tid = threadIdx.x;

  // --- 6 gate heads: sigmoid( softmax(z) . W2 + b2 ), z = xy@W1 + b1 (raw zP + bias) ---
  for (int g = 0; g < 6; ++g) {
    const float* zb0 = P.zP + (g * 2) * (128 * 1024) + b * 1024;
    const float* zb1 = zb0 + 128 * 1024;
    const float* b1 = (g < 3) ? (P.copb1 + g * 1024) : (P.wopb1 + (g - 3) * 1024);
    const float* W2 = (g < 3) ? (P.copW2 + g * 1024) : (P.wopW2 + (g - 3) * 1024);
    float m = -INFINITY, s = 0.f, wacc = 0.f;
    for (int h = tid; h < 1024; h += 256) {
      float z = zb0[h] + zb1[h] + b1[h];
      float w2h = W2[h];
      if (z > m) {
        float e = __expf(m - z);
        s = s * e + 1.f;
        wacc = wacc * e + w2h;
        m = z;
      } else {
        float e = __expf(z - m);
        s += e;
        wacc = fmaf(w2h, e, wacc);
      }
    }
    block_softdot(m, s, wacc, sc);
    if (tid == 0) {
      float b2 = (g < 3) ? P.copb2[g] : P.wopb2[g - 3];
      float zz = wacc / s + b2;
      shg[g] = 1.f / (1.f + __expf(-zz));
    }
  }

  // --- ||relu(z'_ctrl)|| and ||relu(z'_work)|| ---
  float s6 = 0.f, s7 = 0.f;
  {
    const float* z60 = P.zP + 12 * (128 * 1024) + b * 1024;
    const float* z61 = z60 + 128 * 1024;
    const float* z70 = P.zP + 14 * (128 * 1024) + b * 1024;
    const float* z71 = z70 + 128 * 1024;
    float ix = P.ixy[b], iw = P.iwxy[b];
    for (int h = tid; h < 1024; h += 256) {
      float z6 = (z60[h] + z61[h]) * (ix * P.invW[516 + h]);
      float r6 = fmaxf(z6, 0.f); s6 += r6 * r6;
      float z7 = (z70[h] + z71[h]) * (iw * P.invW[2052 + h]);
      float r7 = fmaxf(z7, 0.f); s7 += r7 * r7;
    }
  }
  s6 = block_sum(s6, sc);
  s7 = block_sum(s7, sc);
  float inv_n0 = 1.f / fmaxf(sqrtf(s6), 1e-12f);
  float inv_n1 = 1.f / fmaxf(sqrtf(s7), 1e-12f);

  // --- sel = softmax5( relu(z'_sel) @ selW2^T ) (raw kbP sums) ---
  if (tid < 5) {
    float l = 0.f;
    for (int ks = 0; ks < 8; ++ks) l += P.kbP[(ks * 128 + b) * 1032 + 1024 + tid];
    shsel[tid] = l;
  }
  __syncthreads();
  if (tid == 0) {
    float mx = shsel[0];
    for (int j = 1; j < 5; ++j) mx = fmaxf(mx, shsel[j]);
    float es = 0.f, e[5];
    for (int j = 0; j < 5; ++j) { e[j] = __expf(shsel[j] - mx); es += e[j]; }
    for (int j = 0; j < 5; ++j) shsel[j] = e[j] / es;
  }
  __syncthreads();

  // --- new_control / new_work + output ---
  float ncv[2], nwv[2];
#pragma unroll
  for (int i = 0; i < 2; ++i) {
    int v = tid + i * 256;
    float a = 0.f, c = 0.f;
    for (int ks = 0; ks < 8; ++ks) {
      const float* row = P.kbP + (ks * 128 + b) * 1032;
      a += row[v];
      c += row[512 + v];
    }
    ncv[i] = tanhf(a * inv_n0 * P.invW[1540 + v]);
    nwv[i] = tanhf(c * inv_n1 * P.invW[3076 + v]);
    float wv = P.wvec[b * 512 + v];
    float o = shsel[0] * wv;
#pragma unroll
    for (int j = 0; j < 4; ++j) o += shsel[1 + j] * P.osym[j * 512 + v];
    P.out[(b * TT + t) * 512 + v] = o;
  }

  // --- stack soft ops ---
  float pc[4], pw[4];
#pragma unroll
  for (int n = 0; n < 4; ++n) { pc[n] = P.cp[b * 4 + n]; pw[n] = P.wp[b * 4 + n]; }
  float G0 = shg[0], G1 = shg[1], G2 = shg[2];
  float Hh0 = shg[3], Hh1 = shg[4], Hh2 = shg[5];
  float ppc[4], ppoc[4], ppw[4], ppow[4], npc[4], npw[4];
#pragma unroll
  for (int n = 0; n < 4; ++n) {
    ppc[n] = pc[(n + 3) & 3]; ppoc[n] = pc[(n + 1) & 3];
    ppw[n] = pw[(n + 3) & 3]; ppow[n] = pw[(n + 1) & 3];
    npc[n] = G0 * ppc[n] + G1 * ppoc[n] + G2 * pc[n];
    npw[n] = Hh0 * ppw[n] + Hh1 * ppow[n] + Hh2 * pw[n];
  }
  float shc = P.csharp[0], shw = P.wsharp[0];
  float pcn[4], pwn[4], sumc = 0.f, sumw = 0.f;
#pragma unroll
  for (int n = 0; n < 4; ++n) {
    float sp = powf(fmaxf(npc[n], 0.f), shc);
    float sq = powf(fmaxf(npw[n], 0.f), shw);
    pcn[n] = sp; pwn[n] = sq; sumc += sp; sumw += sq;
  }
  sumc += 1e-12f; sumw += 1e-12f;
#pragma unroll
  for (int n = 0; n < 4; ++n) { pcn[n] /= sumc; pwn[n] /= sumw; }

  float newC[4][2], newW[4][2];
#pragma unroll
  for (int i = 0; i < 2; ++i) {
    int v = tid + i * 256;
#pragma unroll
    for (int n = 0; n < 4; ++n) {
      float s = P.cS[(b * 4 + n) * 512 + v];
      float t1 = G0 * (s * (1.f - ppc[n]) + ncv[i] * ppc[n]) + (G1 + G2) * s;
      newC[n][i] = t1;
      P.cS[(b * 4 + n) * 512 + v] = t1;
      float s2 = P.wS[(b * 4 + n) * 512 + v];
      float t2 = Hh0 * (s2 * (1.f - ppw[n]) + nwv[i] * ppw[n]) + (Hh1 + Hh2) * s2;
      newW[n][i] = t2;
      P.wS[(b * 4 + n) * 512 + v] = t2;
    }
  }
  __syncthreads();   // all reads of cp/wp/wvec done before prep overwrites
  if (t + 1 < TT) prep_step(P, b, t + 1, pcn, pwn, newC, newW, sc);
}

// ---------------- launch ----------------
extern "C" void kernel_launch(void* const* d_in, const int* in_sizes, int n_in,
                              void* d_out, int out_size, void* d_ws, size_t ws_size,
                              hipStream_t stream) {
  Params P;
  const float* const* in = (const float* const*)d_in;
  P.x = in[0]; P.Wisin1 = in[1]; P.Wisin2 = in[2];
  P.copW1 = in[3]; P.copb1 = in[4]; P.copW2 = in[5]; P.copb2 = in[6];
  P.wopW1 = in[7]; P.wopb1 = in[8]; P.wopW2 = in[9]; P.wopb2 = in[10];
  P.ctrlW1 = in[11]; P.ctrlW2 = in[12]; P.workW1 = in[13]; P.workW2 = in[14];
  P.selW1 = in[15]; P.selW2 = in[16]; P.osym = in[17]; P.initv = in[18];
  P.csharp = in[19]; P.wsharp = in[20];

  float* w = (float*)d_ws;
  P.cS = w;   w += 128 * 4 * 512;
  P.cp = w;   w += 128 * 4;
  P.wS = w;   w += 128 * 4 * 512;
  P.wp = w;   w += 128 * 4;
  P.wvec = w; w += 128 * 512;
  P.xy = w;   w += 128 * 512;
  P.wxy = w;  w += 128 * 512;
  P.sxy = w;  w += 128 * 512;
  P.ixy = w;  w += 128;
  P.iwxy = w; w += 128;
  P.isxy = w; w += 128;
  P.zP = w;   w += 9 * 2 * 128 * 1024;
  P.kbP = w;  w += 8 * 128 * 1032;
  P.invW = w; w += 4612;
  P.out = (float*)d_out;

  Knorm<<<1153, 256, 0, stream>>>(P);
  K0<<<128, 256, 0, stream>>>(P);
  for (int t = 0; t < TT; ++t) {
    KA<<<144, 256, 0, stream>>>(P);
    KB<<<136, 128, 0, stream>>>(P);
    KC<<<128, 256, 0, stream>>>(P, t);
  }
}

// Round 3
// 16486.598 us; speedup vs baseline: 1.1943x; 1.1943x over previous
//
#include <hip/hip_runtime.h>
#include <math.h>

// Neuralsymbol scan: B=128 rows x T=128 steps, V=512, H=1024, 4-slot soft stacks.
// R2: KA (9 first-layer GEMMs) -> bf16 MFMA 16x16x32 with split-2 (hi/lo) operands,
// 3 products, fp32 accumulate (~1.5e-5 rel err). Weights split once per call (Kconv);
// activations split in prep_step. zP now single full-K slice per GEMM [9][128][1024].
// KB (fp32 GEMM) and KC unchanged except zP indexing.

#define BB 128
#define TT 128
#define VV 512
#define HH 1024

typedef __attribute__((ext_vector_type(8))) short bf16x8;
typedef __attribute__((ext_vector_type(4))) float f32x4;

struct Params {
  const float *x, *Wisin1, *Wisin2, *copW1, *copb1, *copW2, *copb2,
              *wopW1, *wopb1, *wopW2, *wopb2, *ctrlW1, *ctrlW2, *workW1, *workW2,
              *selW1, *selW2, *osym, *initv, *csharp, *wsharp;
  float *cS, *cp, *wS, *wp, *wvec, *xy, *wxy, *sxy, *ixy, *iwxy, *isxy,
        *zP, *kbP, *invW, *out;
  unsigned short *xyh, *xyl, *wxyh, *wxyl, *sxyh, *sxyl, *Wbh, *Wbl;
};

// ---------------- bf16 split helpers ----------------
__device__ inline unsigned short f2bf(float x) {
  union { float f; unsigned u; } c; c.f = x;
  unsigned r = (c.u + 0x7FFFu + ((c.u >> 16) & 1u)) >> 16;
  return (unsigned short)r;
}
__device__ inline float bf2f(unsigned short h) {
  union { unsigned u; float f; } c; c.u = ((unsigned)h) << 16;
  return c.f;
}

// ---------------- reductions (256-thread blocks, 4 waves) ----------------
__device__ inline float block_sum(float v, volatile float* sc) {
#pragma unroll
  for (int off = 32; off; off >>= 1) v += __shfl_down(v, off, 64);
  __syncthreads();                      // guard previous use of sc
  if ((threadIdx.x & 63) == 0) sc[threadIdx.x >> 6] = v;
  __syncthreads();
  return sc[0] + sc[1] + sc[2] + sc[3];
}

// online (max, sum e^{z-max}, sum e^{z-max}*w) merge across 256 threads
__device__ inline void block_softdot(float& m, float& s, float& w, volatile float* sc) {
#pragma unroll
  for (int off = 32; off; off >>= 1) {
    float m2 = __shfl_down(m, off, 64);
    float s2 = __shfl_down(s, off, 64);
    float w2 = __shfl_down(w, off, 64);
    float M = fmaxf(m, m2);
    float e1 = __expf(m - M), e2 = __expf(m2 - M);
    s = s * e1 + s2 * e2;
    w = w * e1 + w2 * e2;
    m = M;
  }
  __syncthreads();
  if ((threadIdx.x & 63) == 0) {
    int wid = threadIdx.x >> 6;
    sc[wid * 3 + 0] = m; sc[wid * 3 + 1] = s; sc[wid * 3 + 2] = w;
  }
  __syncthreads();
  float M = sc[0], S = sc[1], W = sc[2];
#pragma unroll
  for (int i = 1; i < 4; ++i) {
    float m2 = sc[i * 3], s2 = sc[i * 3 + 1], w2 = sc[i * 3 + 2];
    float nm = fmaxf(M, m2);
    float e1 = __expf(M - nm), e2 = __expf(m2 - nm);
    S = S * e1 + s2 * e2; W = W * e1 + w2 * e2; M = nm;
  }
  m = M; s = S; w = W;
}

// ---------------- Knorm: inverse row norms of normalized-weight matrices ----------------
__global__ __launch_bounds__(256) void Knorm(Params P) {
  int row = blockIdx.x * 4 + (threadIdx.x >> 6);
  if (row >= 4612) return;
  int lane = threadIdx.x & 63;
  const float* src; int K; int dst;
  if (row < 4)        { src = P.Wisin1 + row * 512;            K = 512;  dst = row; }
  else if (row < 516) { int v = row - 4;    src = P.Wisin2 + v * 4;    K = 4;    dst = 4 + v; }
  else if (row < 1540){ int h = row - 516;  src = P.ctrlW1 + h * 512;  K = 512;  dst = 516 + h; }
  else if (row < 2052){ int v = row - 1540; src = P.ctrlW2 + v * 1024; K = 1024; dst = 1540 + v; }
  else if (row < 3076){ int h = row - 2052; src = P.workW1 + h * 512;  K = 512;  dst = 2052 + h; }
  else if (row < 3588){ int v = row - 3076; src = P.workW2 + v * 1024; K = 1024; dst = 3076 + v; }
  else                { int h = row - 3588; src = P.selW1 + h * 512;   K = 512;  dst = 3588 + h; }
  float s = 0.f;
  for (int k = lane; k < K; k += 64) { float x = src[k]; s += x * x; }
#pragma unroll
  for (int off = 32; off; off >>= 1) s += __shfl_down(s, off, 64);
  if (lane == 0) P.invW[dst] = 1.f / fmaxf(sqrtf(s), 1e-12f);
}

// ---------------- Kconv: split the 9 first-layer W matrices into bf16 hi/lo ----------------
__global__ __launch_bounds__(256) void Kconv(Params P) {
  const int total = 9 * 1024 * 512;
  for (int e = blockIdx.x * 256 + threadIdx.x; e < total; e += gridDim.x * 256) {
    int m = e >> 19, rem = e & ((1 << 19) - 1);
    const float* base;
    if (m < 3)       base = P.copW1 + (m << 19);
    else if (m < 6)  base = P.wopW1 + ((m - 3) << 19);
    else if (m == 6) base = P.ctrlW1;
    else if (m == 7) base = P.workW1;
    else             base = P.selW1;
    float v = base[rem];
    unsigned short h = f2bf(v);
    P.Wbh[e] = h;
    P.Wbl[e] = f2bf(v - bf2f(h));
  }
}

// ---------------- prep: pop stacks, typ, xy/wxy/sxy (+bf16 splits, norm scalars) ----------------
__device__ void prep_step(const Params& P, int b, int tn,
                          const float pcn[4], const float pwn[4],
                          const float newC[4][2], const float newW[4][2],
                          volatile float* sc) {
  int tid = threadIdx.x;
  // write rolled (post-pop) pointers
  if (tid == 0) {
#pragma unroll
    for (int n = 0; n < 4; ++n) {
      P.cp[b * 4 + n] = pcn[(n + 1) & 3];
      P.wp[b * 4 + n] = pwn[(n + 1) & 3];
    }
  }
  float ctl[2], wrk[2], inp[2];
#pragma unroll
  for (int i = 0; i < 2; ++i) {
    int v = tid + i * 256;
    float c = 0.f, w = 0.f;
#pragma unroll
    for (int n = 0; n < 4; ++n) { c += pcn[n] * newC[n][i]; w += pwn[n] * newW[n][i]; }
    ctl[i] = c; wrk[i] = w;
    P.wvec[b * 512 + v] = w;
    inp[i] = P.x[(b * TT + tn) * 512 + v];
  }
  // reduce: ||inp||^2 and 4 dots with W_isin1
  float r0 = inp[0] * inp[0] + inp[1] * inp[1];
  float d[4];
#pragma unroll
  for (int j = 0; j < 4; ++j)
    d[j] = inp[0] * P.Wisin1[j * 512 + tid] + inp[1] * P.Wisin1[j * 512 + tid + 256];
  r0 = block_sum(r0, sc);
#pragma unroll
  for (int j = 0; j < 4; ++j) d[j] = block_sum(d[j], sc);
  float inv_in = 1.f / fmaxf(sqrtf(r0), 1e-12f);
  // relu -> softmax4 -> normalize (redundant on all threads; deterministic)
  float a[4];
#pragma unroll
  for (int j = 0; j < 4; ++j) a[j] = fmaxf(d[j] * inv_in * P.invW[j], 0.f);
  float mx = fmaxf(fmaxf(a[0], a[1]), fmaxf(a[2], a[3]));
  float e[4], es = 0.f;
#pragma unroll
  for (int j = 0; j < 4; ++j) { e[j] = __expf(a[j] - mx); es += e[j]; }
  float q[4], qs = 0.f;
#pragma unroll
  for (int j = 0; j < 4; ++j) { q[j] = e[j] / es; qs += q[j] * q[j]; }
  float qi = 1.f / fmaxf(sqrtf(qs), 1e-12f);
  float qn[4];
#pragma unroll
  for (int j = 0; j < 4; ++j) qn[j] = q[j] * qi;

  float xys = 0.f, wxs = 0.f, sxs = 0.f;
#pragma unroll
  for (int i = 0; i < 2; ++i) {
    int v = tid + i * 256;
    float dq = 0.f;
#pragma unroll
    for (int j = 0; j < 4; ++j) dq += qn[j] * P.Wisin2[v * 4 + j];
    float typ = tanhf(dq * P.invW[4 + v]);
    float xyv = ctl[i] * typ;
    float wxv = wrk[i] * inp[i] * typ;
    float sxv = ctl[i] * wrk[i] * typ;
    P.xy[b * 512 + v] = xyv;
    P.wxy[b * 512 + v] = wxv;
    P.sxy[b * 512 + v] = sxv;
    // bf16 hi/lo splits for MFMA KA
    unsigned short hh;
    hh = f2bf(xyv); P.xyh[b * 512 + v] = hh; P.xyl[b * 512 + v] = f2bf(xyv - bf2f(hh));
    hh = f2bf(wxv); P.wxyh[b * 512 + v] = hh; P.wxyl[b * 512 + v] = f2bf(wxv - bf2f(hh));
    hh = f2bf(sxv); P.sxyh[b * 512 + v] = hh; P.sxyl[b * 512 + v] = f2bf(sxv - bf2f(hh));
    xys += xyv * xyv; wxs += wxv * wxv; sxs += sxv * sxv;
  }
  xys = block_sum(xys, sc);
  wxs = block_sum(wxs, sc);
  sxs = block_sum(sxs, sc);
  if (tid == 0) {
    P.ixy[b]  = 1.f / fmaxf(sqrtf(xys), 1e-12f);
    P.iwxy[b] = 1.f / fmaxf(sqrtf(wxs), 1e-12f);
    P.isxy[b] = 1.f / fmaxf(sqrtf(sxs), 1e-12f);
  }
}

// ---------------- K0: init stacks (hard push of init vec) + prep(t=0) ----------------
__global__ __launch_bounds__(256) void K0(Params P) {
  __shared__ float sc[16];
  int b = blockIdx.x, tid = threadIdx.x;
  float newC[4][2], newW[4][2];
#pragma unroll
  for (int i = 0; i < 2; ++i) {
    int v = tid + i * 256;
    float iv = P.initv[v];
#pragma unroll
    for (int n = 0; n < 4; ++n) {
      float val = (n == 1) ? iv : 1e-6f;
      P.cS[(b * 4 + n) * 512 + v] = val;
      P.wS[(b * 4 + n) * 512 + v] = val;
      newC[n][i] = val; newW[n][i] = val;
    }
  }
  float p0[4] = {0.f, 1.f, 0.f, 0.f};   // pointer after initial hard push
  __syncthreads();
  prep_step(P, b, 0, p0, p0, newC, newW, sc);
}

// ---------------- KA: 9 first-layer GEMMs via bf16-split MFMA ----------------
// grid 144: blk = m*16 + ct ; block tile 128 rows x 64 cols, full K=512.
// out[r][h] = sum_k X[r][k]*W[h][k]  (NT GEMM: A,B frags load identically, K-major).
// LDS in fragment order (lane-linear 16B) -> conflict-free ds_read_b128.
__global__ __launch_bounds__(256) void KA(Params P) {
  int blk = blockIdx.x;
  int m_id = blk >> 4, ct = blk & 15;
  int h0 = ct * 64;
  const unsigned short *Xh, *Xl;
  if (m_id <= 6)      { Xh = P.xyh;  Xl = P.xyl; }
  else if (m_id == 7) { Xh = P.wxyh; Xl = P.wxyl; }
  else                { Xh = P.sxyh; Xl = P.sxyl; }
  __shared__ unsigned short lds[24576];   // [XH 8K][XL 8K][WH 4K][WL 4K] ushorts
  int tid = threadIdx.x;
  int w = tid >> 6, lane = tid & 63, wm = w >> 1, wn = w & 1;
  f32x4 acc[4][2];
#pragma unroll
  for (int mf = 0; mf < 4; ++mf)
#pragma unroll
    for (int nf = 0; nf < 2; ++nf) acc[mf][nf] = (f32x4)(0.0f);
  const int wbase = (m_id * 1024 + h0) * 512;
  for (int kb = 0; kb < 8; ++kb) {
    int k0 = kb * 64;
    __syncthreads();
    // X tile: 128 rows x 64 k (hi+lo), fragment-order LDS
#pragma unroll
    for (int it = 0; it < 4; ++it) {
      int c = it * 256 + tid;
      int r = c >> 3, o = c & 7;
      int so = (r << 9) + k0 + (o << 3);
      int doff = (((r >> 4) * 2 + (o >> 2)) * 64 + ((r & 15) | ((o & 3) << 4))) * 8;
      *(uint4*)&lds[doff]        = *(const uint4*)&Xh[so];
      *(uint4*)&lds[8192 + doff] = *(const uint4*)&Xl[so];
    }
    // W tile: 64 rows(h) x 64 k (hi+lo)
#pragma unroll
    for (int it = 0; it < 2; ++it) {
      int c = it * 256 + tid;
      int hh = c >> 3, o = c & 7;
      int so = wbase + (hh << 9) + k0 + (o << 3);
      int doff = (((hh >> 4) * 2 + (o >> 2)) * 64 + ((hh & 15) | ((o & 3) << 4))) * 8;
      *(uint4*)&lds[16384 + doff] = *(const uint4*)&P.Wbh[so];
      *(uint4*)&lds[20480 + doff] = *(const uint4*)&P.Wbl[so];
    }
    __syncthreads();
#pragma unroll
    for (int kc = 0; kc < 2; ++kc) {
      bf16x8 ah[4], al[4], bh[2], bl[2];
#pragma unroll
      for (int mf = 0; mf < 4; ++mf) {
        int off = (((wm * 4 + mf) * 2 + kc) * 64 + lane) * 8;
        ah[mf] = *(bf16x8*)&lds[off];
        al[mf] = *(bf16x8*)&lds[8192 + off];
      }
#pragma unroll
      for (int nf = 0; nf < 2; ++nf) {
        int off = (((wn * 2 + nf) * 2 + kc) * 64 + lane) * 8;
        bh[nf] = *(bf16x8*)&lds[16384 + off];
        bl[nf] = *(bf16x8*)&lds[20480 + off];
      }
#pragma unroll
      for (int mf = 0; mf < 4; ++mf)
#pragma unroll
        for (int nf = 0; nf < 2; ++nf) {
          acc[mf][nf] = __builtin_amdgcn_mfma_f32_16x16x32_bf16(ah[mf], bh[nf], acc[mf][nf], 0, 0, 0);
          acc[mf][nf] = __builtin_amdgcn_mfma_f32_16x16x32_bf16(ah[mf], bl[nf], acc[mf][nf], 0, 0, 0);
          acc[mf][nf] = __builtin_amdgcn_mfma_f32_16x16x32_bf16(al[mf], bh[nf], acc[mf][nf], 0, 0, 0);
        }
    }
  }
  // epilogue: C layout col=lane&15, row=(lane>>4)*4+reg (m89/m91-verified)
  float* zdst = P.zP + m_id * 131072;
#pragma unroll
  for (int mf = 0; mf < 4; ++mf)
#pragma unroll
    for (int nf = 0; nf < 2; ++nf)
#pragma unroll
      for (int r = 0; r < 4; ++r) {
        int row = wm * 64 + mf * 16 + ((lane >> 4) << 2) + r;
        int col = h0 + wn * 32 + nf * 16 + (lane & 15);
        zdst[(row << 10) + col] = acc[mf][nf][r];
      }
}

// ---------------- KB: second-layer GEMMs (relu + fold scales on load), K split in 8 ----------------
// grid 136: w = tile*8 + ks ; tile<8 ctrl cols, 8..15 work cols, 16 sel (5 cols)
__global__ __launch_bounds__(128) void KB(Params P) {
  int w = blockIdx.x;
  int ks = w & 7, tile = w >> 3;
  int zm = (tile < 8) ? 6 : (tile < 16 ? 7 : 8);
  int colbase = (tile < 16) ? tile * 64 : 1024;
  int k0 = ks * 128;
  __shared__ float at[32][132];
  __shared__ float wt2[32][68];
  float acc[8][8];
#pragma unroll
  for (int j = 0; j < 8; ++j)
#pragma unroll
    for (int i = 0; i < 8; ++i) acc[j][i] = 0.f;
  int cg = threadIdx.x & 7, rg = threadIdx.x >> 3;
  const float* zb0 = P.zP + zm * 131072;
  const float* ix = (zm == 6) ? P.ixy : (zm == 7 ? P.iwxy : P.isxy);
  int ioff = (zm == 6) ? 516 : (zm == 7 ? 2052 : 3588);
  for (int kc = 0; kc < 128; kc += 32) {
#pragma unroll
    for (int i = 0; i < 32; ++i) {
      int flat = i * 128 + threadIdx.x;
      int r = flat >> 5, k = flat & 31;
      int h = k0 + kc + k;
      float z = zb0[r * 1024 + h];
      at[k][r] = fmaxf(z * (ix[r] * P.invW[ioff + h]), 0.f);
    }
#pragma unroll
    for (int i = 0; i < 16; ++i) {
      int flat = i * 128 + threadIdx.x;
      int c = flat >> 5, k = flat & 31;
      int h = k0 + kc + k;
      float val;
      if (tile < 8)       val = P.ctrlW2[(tile * 64 + c) * 1024 + h];
      else if (tile < 16) val = P.workW2[((tile - 8) * 64 + c) * 1024 + h];
      else                val = (c < 5) ? P.selW2[c * 1024 + h] : 0.f;
      wt2[k][c] = val;
    }
    __syncthreads();
    for (int k = 0; k < 32; ++k) {
      float a[8], bb[8];
      *(float4*)&a[0] = *(const float4*)&at[k][rg * 8];
      *(float4*)&a[4] = *(const float4*)&at[k][rg * 8 + 4];
      *(float4*)&bb[0] = *(const float4*)&wt2[k][cg * 8];
      *(float4*)&bb[4] = *(const float4*)&wt2[k][cg * 8 + 4];
#pragma unroll
      for (int j = 0; j < 8; ++j)
#pragma unroll
        for (int i = 0; i < 8; ++i) acc[j][i] = fmaf(a[j], bb[i], acc[j][i]);
    }
    __syncthreads();
  }
#pragma unroll
  for (int j = 0; j < 8; ++j) {
    int r = rg * 8 + j;
    int col = colbase + cg * 8;
    if (col + 8 <= 1032) {
      float* dst = P.kbP + (ks * 128 + r) * 1032 + col;
      float4 v0 = make_float4(acc[j][0], acc[j][1], acc[j][2], acc[j][3]);
      float4 v1 = make_float4(acc[j][4], acc[j][5], acc[j][6], acc[j][7]);
      *(float4*)&dst[0] = v0;
      *(float4*)&dst[4] = v1;
    }
  }
}

// ---------------- KC: gates, norms, sel, out, stack soft-ops, + prep(t+1) ----------------
__global__ __launch_bounds__(256) void KC(Params P, int t) {
  __shared__ float sc[16];
  __shared__ float shg[6];
  __shared__ float shsel[5];
  int b = blockIdx.x, tid = threadIdx.x;

  // --- 6 gate heads: sigmoid( softmax(z) . W2 + b2 ), z = xy@W1 + b1 (raw zP + bias) ---
  for (int g = 0; g < 6; ++g) {
    const float* zb = P.zP + g * 131072 + b * 1024;
    const float* b1 = (g < 3) ? (P.copb1 + g * 1024) : (P.wopb1 + (g - 3) * 1024);
    const float* W2 = (g < 3) ? (P.copW2 + g * 1024) : (P.wopW2 + (g - 3) * 1024);
    float m = -INFINITY, s = 0.f, wacc = 0.f;
    for (int h = tid; h < 1024; h += 256) {
      float z = zb[h] + b1[h];
      float w2h = W2[h];
      if (z > m) {
        float e = __expf(m - z);
        s = s * e + 1.f;
        wacc = wacc * e + w2h;
        m = z;
      } else {
        float e = __expf(z - m);
        s += e;
        wacc = fmaf(w2h, e, wacc);
      }
    }
    block_softdot(m, s, wacc, sc);
    if (tid == 0) {
      float b2 = (g < 3) ? P.copb2[g] : P.wopb2[g - 3];
      float zz = wacc / s + b2;
      shg[g] = 1.f / (1.f + __expf(-zz));
    }
  }

  // --- ||relu(z'_ctrl)|| and ||relu(z'_work)|| ---
  float s6 = 0.f, s7 = 0.f;
  {
    const float* z6p = P.zP + 6 * 131072 + b * 1024;
    const float* z7p = P.zP + 7 * 131072 + b * 1024;
    float ix = P.ixy[b], iw = P.iwxy[b];
    for (int h = tid; h < 1024; h += 256) {
      float z6 = z6p[h] * (ix * P.invW[516 + h]);
      float r6 = fmaxf(z6, 0.f); s6 += r6 * r6;
      float z7 = z7p[h] * (iw * P.invW[2052 + h]);
      float r7 = fmaxf(z7, 0.f); s7 += r7 * r7;
    }
  }
  s6 = block_sum(s6, sc);
  s7 = block_sum(s7, sc);
  float inv_n0 = 1.f / fmaxf(sqrtf(s6), 1e-12f);
  float inv_n1 = 1.f / fmaxf(sqrtf(s7), 1e-12f);

  // --- sel = softmax5( relu(z'_sel) @ selW2^T ) (raw kbP sums) ---
  if (tid < 5) {
    float l = 0.f;
    for (int ks = 0; ks < 8; ++ks) l += P.kbP[(ks * 128 + b) * 1032 + 1024 + tid];
    shsel[tid] = l;
  }
  __syncthreads();
  if (tid == 0) {
    float mx = shsel[0];
    for (int j = 1; j < 5; ++j) mx = fmaxf(mx, shsel[j]);
    float es = 0.f, e[5];
    for (int j = 0; j < 5; ++j) { e[j] = __expf(shsel[j] - mx); es += e[j]; }
    for (int j = 0; j < 5; ++j) shsel[j] = e[j] / es;
  }
  __syncthreads();

  // --- new_control / new_work + output ---
  float ncv[2], nwv[2];
#pragma unroll
  for (int i = 0; i < 2; ++i) {
    int v = tid + i * 256;
    float a = 0.f, c = 0.f;
    for (int ks = 0; ks < 8; ++ks) {
      const float* row = P.kbP + (ks * 128 + b) * 1032;
      a += row[v];
      c += row[512 + v];
    }
    ncv[i] = tanhf(a * inv_n0 * P.invW[1540 + v]);
    nwv[i] = tanhf(c * inv_n1 * P.invW[3076 + v]);
    float wv = P.wvec[b * 512 + v];
    float o = shsel[0] * wv;
#pragma unroll
    for (int j = 0; j < 4; ++j) o += shsel[1 + j] * P.osym[j * 512 + v];
    P.out[(b * TT + t) * 512 + v] = o;
  }

  // --- stack soft ops ---
  float pc[4], pw[4];
#pragma unroll
  for (int n = 0; n < 4; ++n) { pc[n] = P.cp[b * 4 + n]; pw[n] = P.wp[b * 4 + n]; }
  float G0 = shg[0], G1 = shg[1], G2 = shg[2];
  float Hh0 = shg[3], Hh1 = shg[4], Hh2 = shg[5];
  float ppc[4], ppoc[4], ppw[4], ppow[4], npc[4], npw[4];
#pragma unroll
  for (int n = 0; n < 4; ++n) {
    ppc[n] = pc[(n + 3) & 3]; ppoc[n] = pc[(n + 1) & 3];
    ppw[n] = pw[(n + 3) & 3]; ppow[n] = pw[(n + 1) & 3];
    npc[n] = G0 * ppc[n] + G1 * ppoc[n] + G2 * pc[n];
    npw[n] = Hh0 * ppw[n] + Hh1 * ppow[n] + Hh2 * pw[n];
  }
  float shc = P.csharp[0], shw = P.wsharp[0];
  float pcn[4], pwn[4], sumc = 0.f, sumw = 0.f;
#pragma unroll
  for (int n = 0; n < 4; ++n) {
    float sp = powf(fmaxf(npc[n], 0.f), shc);
    float sq = powf(fmaxf(npw[n], 0.f), shw);
    pcn[n] = sp; pwn[n] = sq; sumc += sp; sumw += sq;
  }
  sumc += 1e-12f; sumw += 1e-12f;
#pragma unroll
  for (int n = 0; n < 4; ++n) { pcn[n] /= sumc; pwn[n] /= sumw; }

  float newC[4][2], newW[4][2];
#pragma unroll
  for (int i = 0; i < 2; ++i) {
    int v = tid + i * 256;
#pragma unroll
    for (int n = 0; n < 4; ++n) {
      float s = P.cS[(b * 4 + n) * 512 + v];
      float t1 = G0 * (s * (1.f - ppc[n]) + ncv[i] * ppc[n]) + (G1 + G2) * s;
      newC[n][i] = t1;
      P.cS[(b * 4 + n) * 512 + v] = t1;
      float s2 = P.wS[(b * 4 + n) * 512 + v];
      float t2 = Hh0 * (s2 * (1.f - ppw[n]) + nwv[i] * ppw[n]) + (Hh1 + Hh2) * s2;
      newW[n][i] = t2;
      P.wS[(b * 4 + n) * 512 + v] = t2;
    }
  }
  __syncthreads();   // all reads of cp/wp/wvec done before prep overwrites
  if (t + 1 < TT) prep_step(P, b, t + 1, pcn, pwn, newC, newW, sc);
}

// ---------------- launch ----------------
extern "C" void kernel_launch(void* const* d_in, const int* in_sizes, int n_in,
                              void* d_out, int out_size, void* d_ws, size_t ws_size,
                              hipStream_t stream) {
  Params P;
  const float* const* in = (const float* const*)d_in;
  P.x = in[0]; P.Wisin1 = in[1]; P.Wisin2 = in[2];
  P.copW1 = in[3]; P.copb1 = in[4]; P.copW2 = in[5]; P.copb2 = in[6];
  P.wopW1 = in[7]; P.wopb1 = in[8]; P.wopW2 = in[9]; P.wopb2 = in[10];
  P.ctrlW1 = in[11]; P.ctrlW2 = in[12]; P.workW1 = in[13]; P.workW2 = in[14];
  P.selW1 = in[15]; P.selW2 = in[16]; P.osym = in[17]; P.initv = in[18];
  P.csharp = in[19]; P.wsharp = in[20];

  float* w = (float*)d_ws;
  P.cS = w;   w += 128 * 4 * 512;
  P.cp = w;   w += 128 * 4;
  P.wS = w;   w += 128 * 4 * 512;
  P.wp = w;   w += 128 * 4;
  P.wvec = w; w += 128 * 512;
  P.xy = w;   w += 128 * 512;
  P.wxy = w;  w += 128 * 512;
  P.sxy = w;  w += 128 * 512;
  P.ixy = w;  w += 128;
  P.iwxy = w; w += 128;
  P.isxy = w; w += 128;
  P.zP = w;   w += 9 * 128 * 1024;
  P.kbP = w;  w += 8 * 128 * 1032;
  P.invW = w; w += 4616;                       // 4612 rounded to 16B multiple
  P.xyh  = (unsigned short*)w; w += 32768;     // each: 128*512 ushorts = 32768 floats
  P.xyl  = (unsigned short*)w; w += 32768;
  P.wxyh = (unsigned short*)w; w += 32768;
  P.wxyl = (unsigned short*)w; w += 32768;
  P.sxyh = (unsigned short*)w; w += 32768;
  P.sxyl = (unsigned short*)w; w += 32768;
  P.Wbh  = (unsigned short*)w; w += 9 * 1024 * 512 / 2;
  P.Wbl  = (unsigned short*)w; w += 9 * 1024 * 512 / 2;
  P.out = (float*)d_out;

  Knorm<<<1153, 256, 0, stream>>>(P);
  Kconv<<<4608, 256, 0, stream>>>(P);
  K0<<<128, 256, 0, stream>>>(P);
  for (int t = 0; t < TT; ++t) {
    KA<<<144, 256, 0, stream>>>(P);
    KB<<<136, 128, 0, stream>>>(P);
    KC<<<128, 256, 0, stream>>>(P, t);
  }
}